// Round 2
// baseline (589.533 us; speedup 1.0000x reference)
//
#include <hip/hip_runtime.h>
#include <cstdint>
#include <cstddef>

// Problem dims (fixed by setup_inputs)
#define B_N 8
#define Q_N 1024
#define K_N 4096
#define H_N 512
#define C_N 1024        // 2H
#define R_N (B_N * Q_N) // 8192 rows total

typedef short bf16x8 __attribute__((ext_vector_type(8)));
typedef float f32x4 __attribute__((ext_vector_type(4)));

typedef const void __attribute__((address_space(1))) gas_void;
typedef void __attribute__((address_space(3))) las_void;

__device__ __forceinline__ unsigned short f2bf(float f) {
    union { float f; unsigned u; } v; v.f = f;
    unsigned u = v.u;
    u += 0x7FFFu + ((u >> 16) & 1u);   // RNE
    return (unsigned short)(u >> 16);
}
__device__ __forceinline__ float bf2f(unsigned short h) {
    union { unsigned u; float f; } v; v.u = ((unsigned)h) << 16;
    return v.f;
}

__device__ __forceinline__ f32x4 mfma16(bf16x8 a, bf16x8 b, f32x4 c) {
    return __builtin_amdgcn_mfma_f32_16x16x32_bf16(a, b, c, 0, 0, 0);
}

// ---------------- K0a: fp32 -> bf16 hi/lo split (4 elems/thread) ----------------
__global__ void k_split(const float* __restrict__ x, unsigned short* __restrict__ hi,
                        unsigned short* __restrict__ lo, int n4) {
    int i = blockIdx.x * 256 + threadIdx.x;
    if (i >= n4) return;
    float4 v = reinterpret_cast<const float4*>(x)[i];
    ushort4 h, l;
    h.x = f2bf(v.x); l.x = f2bf(v.x - bf2f(h.x));
    h.y = f2bf(v.y); l.y = f2bf(v.y - bf2f(h.y));
    h.z = f2bf(v.z); l.z = f2bf(v.z - bf2f(h.z));
    h.w = f2bf(v.w); l.w = f2bf(v.w - bf2f(h.w));
    reinterpret_cast<ushort4*>(hi)[i] = h;
    reinterpret_cast<ushort4*>(lo)[i] = l;
}

__global__ void k_cvt(const float* __restrict__ x, unsigned short* __restrict__ hi, int n4) {
    int i = blockIdx.x * 256 + threadIdx.x;
    if (i >= n4) return;
    float4 v = reinterpret_cast<const float4*>(x)[i];
    ushort4 h;
    h.x = f2bf(v.x); h.y = f2bf(v.y); h.z = f2bf(v.z); h.w = f2bf(v.w);
    reinterpret_cast<ushort4*>(hi)[i] = h;
}

// ---------------- K0b: fused context split + transpose ----------------
// One read of fp32 context -> ctxHi, ctxLo (row-major [B][K][H]) and ctxT ([B][H][K], bf16 hi).
// 64x64 tiles; all global accesses vectorized (float4 in, ushort4 out).
__global__ __launch_bounds__(256)
void k_prep_ctx(const float* __restrict__ ctx, unsigned short* __restrict__ ctxHi,
                unsigned short* __restrict__ ctxLo, unsigned short* __restrict__ ctxT) {
    __shared__ unsigned short tile[64][66]; // [h][k], +2 pad keeps 8B align & breaks bank stride
    const int b = blockIdx.z;
    const int k0 = blockIdx.x * 64;
    const int h0 = blockIdx.y * 64;
    const int tx = threadIdx.x & 15;   // 16 x float4 = 64 cols
    const int ty = threadIdx.x >> 4;   // 16 rows per pass
#pragma unroll
    for (int r = 0; r < 64; r += 16) {
        const int k = ty + r;
        const size_t go = ((size_t)b * K_N + k0 + k) * H_N + h0 + tx * 4;
        float4 v = *reinterpret_cast<const float4*>(ctx + go);
        ushort4 h, l;
        h.x = f2bf(v.x); l.x = f2bf(v.x - bf2f(h.x));
        h.y = f2bf(v.y); l.y = f2bf(v.y - bf2f(h.y));
        h.z = f2bf(v.z); l.z = f2bf(v.z - bf2f(h.z));
        h.w = f2bf(v.w); l.w = f2bf(v.w - bf2f(h.w));
        *reinterpret_cast<ushort4*>(ctxHi + go) = h;
        *reinterpret_cast<ushort4*>(ctxLo + go) = l;
        tile[tx * 4 + 0][k] = h.x;
        tile[tx * 4 + 1][k] = h.y;
        tile[tx * 4 + 2][k] = h.z;
        tile[tx * 4 + 3][k] = h.w;
    }
    __syncthreads();
#pragma unroll
    for (int r = 0; r < 64; r += 16) {
        const int h = ty + r;
        ushort4 t4 = *reinterpret_cast<const ushort4*>(&tile[h][tx * 4]);
        *reinterpret_cast<ushort4*>(ctxT + ((size_t)b * H_N + h0 + h) * K_N + k0 + tx * 4) = t4;
    }
}

// ---------------- async stage: 128x32 bf16 tile, global -> LDS, 16B/lane ----------------
__device__ __forceinline__ void stage_tile(const unsigned short* __restrict__ g, int ld,
                                           unsigned short* __restrict__ lds) {
    const int t = threadIdx.x;
    const int wbase = t & ~63;
#pragma unroll
    for (int i = 0; i < 2; i++) {
        int idx = i * 256 + t;
        const unsigned short* ga = g + (size_t)(idx >> 2) * ld + (idx & 3) * 8;
        unsigned short* la = lds + (size_t)(i * 256 + wbase) * 8;
        __builtin_amdgcn_global_load_lds((gas_void*)ga, (las_void*)la, 16, 0, 0);
    }
}

// ---------------- K1: S = output . context^T  (bf16x3 split) + mask in epilogue ----------------
__global__ __launch_bounds__(256, 2)
void k_scores(const unsigned short* __restrict__ outHi, const unsigned short* __restrict__ outLo,
              const unsigned short* __restrict__ ctxHi, const unsigned short* __restrict__ ctxLo,
              const int* __restrict__ mask, float* __restrict__ S) {
    __shared__ unsigned short Ah[128 * 32], Al[128 * 32], Bh[128 * 32], Bl[128 * 32];
    const int b = blockIdx.z;
    const int q0 = blockIdx.y * 128;
    const int k0 = blockIdx.x * 128;
    const unsigned short* Ahg = outHi + ((size_t)b * Q_N + q0) * H_N;
    const unsigned short* Alg = outLo + ((size_t)b * Q_N + q0) * H_N;
    const unsigned short* Bhg = ctxHi + ((size_t)b * K_N + k0) * H_N;
    const unsigned short* Blg = ctxLo + ((size_t)b * K_N + k0) * H_N;
    const int lane = threadIdx.x & 63;
    const int w = threadIdx.x >> 6;
    const int wr = (w >> 1) * 64;
    const int wc = (w & 1) * 64;
    const int fm = lane & 15;
    const int fg = (lane >> 4) * 8;

    f32x4 acc[4][4];
#pragma unroll
    for (int i = 0; i < 4; i++)
#pragma unroll
        for (int j = 0; j < 4; j++) acc[i][j] = (f32x4){0.f, 0.f, 0.f, 0.f};

    for (int kc = 0; kc < H_N; kc += 32) {
        stage_tile(Ahg + kc, H_N, Ah);
        stage_tile(Alg + kc, H_N, Al);
        stage_tile(Bhg + kc, H_N, Bh);
        stage_tile(Blg + kc, H_N, Bl);
        __syncthreads();
        bf16x8 ah[4], al[4], bh[4], bl[4];
#pragma unroll
        for (int i = 0; i < 4; i++) {
            ah[i] = *(const bf16x8*)&Ah[(wr + i * 16 + fm) * 32 + fg];
            al[i] = *(const bf16x8*)&Al[(wr + i * 16 + fm) * 32 + fg];
            bh[i] = *(const bf16x8*)&Bh[(wc + i * 16 + fm) * 32 + fg];
            bl[i] = *(const bf16x8*)&Bl[(wc + i * 16 + fm) * 32 + fg];
        }
#pragma unroll
        for (int i = 0; i < 4; i++)
#pragma unroll
            for (int j = 0; j < 4; j++) {
                acc[i][j] = mfma16(ah[i], bh[j], acc[i][j]);
                acc[i][j] = mfma16(ah[i], bl[j], acc[i][j]);
                acc[i][j] = mfma16(al[i], bh[j], acc[i][j]);
            }
        __syncthreads();
    }
    // epilogue: C/D layout col=lane&15, row=(lane>>4)*4+reg; apply mask -> -1e30
    float* Sb = S + (size_t)b * Q_N * K_N;
    const int orow = (lane >> 4) * 4;
    const int ocol = lane & 15;
#pragma unroll
    for (int i = 0; i < 4; i++)
#pragma unroll
        for (int r = 0; r < 4; r++) {
            int q = q0 + wr + i * 16 + orow + r;
            const size_t rowoff = (size_t)q * K_N + (k0 + wc + ocol);
            float* dst = Sb + rowoff;
            const int* mrow = mask + (size_t)b * Q_N * K_N + rowoff;
#pragma unroll
            for (int j = 0; j < 4; j++) {
                float v = acc[i][j][r];
                dst[j * 16] = mrow[j * 16] ? -1e30f : v;
            }
        }
}

// ---------------- K2: row softmax (mask pre-applied), in-place; also write bf16 P ----------------
__global__ __launch_bounds__(256)
void k_softmax(float* __restrict__ S, unsigned short* __restrict__ pbf) {
    const size_t r = blockIdx.x;
    float* row = S + r * K_N;
    unsigned short* prow = pbf + r * K_N;
    const int t = threadIdx.x;

    float4 v[4];
    float lmax = -1e30f;
#pragma unroll
    for (int i = 0; i < 4; i++) {
        int idx = i * 256 + t;
        float4 s = reinterpret_cast<const float4*>(row)[idx];
        v[i] = s;
        lmax = fmaxf(fmaxf(fmaxf(lmax, s.x), fmaxf(s.y, s.z)), s.w);
    }
#pragma unroll
    for (int off = 32; off >= 1; off >>= 1)
        lmax = fmaxf(lmax, __shfl_xor(lmax, off, 64));
    __shared__ float redm[4];
    __shared__ float reds[4];
    const int wv = t >> 6;
    if ((t & 63) == 0) redm[wv] = lmax;
    __syncthreads();
    const float m = fmaxf(fmaxf(redm[0], redm[1]), fmaxf(redm[2], redm[3]));

    float4 e[4];
    float lsum = 0.f;
#pragma unroll
    for (int i = 0; i < 4; i++) {
        e[i].x = __expf(v[i].x - m);
        e[i].y = __expf(v[i].y - m);
        e[i].z = __expf(v[i].z - m);
        e[i].w = __expf(v[i].w - m);
        lsum += (e[i].x + e[i].y) + (e[i].z + e[i].w);
    }
#pragma unroll
    for (int off = 32; off >= 1; off >>= 1)
        lsum += __shfl_xor(lsum, off, 64);
    if ((t & 63) == 0) reds[wv] = lsum;
    __syncthreads();
    const float inv = 1.0f / (reds[0] + reds[1] + reds[2] + reds[3]);

#pragma unroll
    for (int i = 0; i < 4; i++) {
        int idx = i * 256 + t;
        float4 p;
        p.x = e[i].x * inv; p.y = e[i].y * inv; p.z = e[i].z * inv; p.w = e[i].w * inv;
        reinterpret_cast<float4*>(row)[idx] = p;
        ushort4 pb;
        pb.x = f2bf(p.x); pb.y = f2bf(p.y); pb.z = f2bf(p.z); pb.w = f2bf(p.w);
        reinterpret_cast<ushort4*>(prow)[idx] = pb;
    }
}

// ---------------- K3: mix = P . ctxT^T  (plain bf16), BK=64 two-panel ----------------
__global__ __launch_bounds__(256, 2)
void k_mix(const unsigned short* __restrict__ P, const unsigned short* __restrict__ ctxT,
           unsigned short* __restrict__ mixBf) {
    __shared__ unsigned short A0[128 * 32], A1[128 * 32], B0[128 * 32], B1[128 * 32];
    const int b = blockIdx.z;
    const int q0 = blockIdx.y * 128;
    const int h0 = blockIdx.x * 128;
    const unsigned short* Ag = P + ((size_t)b * Q_N + q0) * K_N;
    const unsigned short* Bg = ctxT + ((size_t)b * H_N + h0) * K_N;
    const int lane = threadIdx.x & 63;
    const int w = threadIdx.x >> 6;
    const int wr = (w >> 1) * 64;
    const int wc = (w & 1) * 64;
    const int fm = lane & 15;
    const int fg = (lane >> 4) * 8;

    f32x4 acc[4][4];
#pragma unroll
    for (int i = 0; i < 4; i++)
#pragma unroll
        for (int j = 0; j < 4; j++) acc[i][j] = (f32x4){0.f, 0.f, 0.f, 0.f};

    for (int kc = 0; kc < K_N; kc += 64) {
        stage_tile(Ag + kc, K_N, A0);
        stage_tile(Ag + kc + 32, K_N, A1);
        stage_tile(Bg + kc, K_N, B0);
        stage_tile(Bg + kc + 32, K_N, B1);
        __syncthreads();
        bf16x8 a[4], bb[4];
#pragma unroll
        for (int i = 0; i < 4; i++) {
            a[i] = *(const bf16x8*)&A0[(wr + i * 16 + fm) * 32 + fg];
            bb[i] = *(const bf16x8*)&B0[(wc + i * 16 + fm) * 32 + fg];
        }
#pragma unroll
        for (int i = 0; i < 4; i++)
#pragma unroll
            for (int j = 0; j < 4; j++) acc[i][j] = mfma16(a[i], bb[j], acc[i][j]);
#pragma unroll
        for (int i = 0; i < 4; i++) {
            a[i] = *(const bf16x8*)&A1[(wr + i * 16 + fm) * 32 + fg];
            bb[i] = *(const bf16x8*)&B1[(wc + i * 16 + fm) * 32 + fg];
        }
#pragma unroll
        for (int i = 0; i < 4; i++)
#pragma unroll
            for (int j = 0; j < 4; j++) acc[i][j] = mfma16(a[i], bb[j], acc[i][j]);
        __syncthreads();
    }
    const int orow = (lane >> 4) * 4;
    const int ocol = lane & 15;
#pragma unroll
    for (int i = 0; i < 4; i++)
#pragma unroll
        for (int r = 0; r < 4; r++) {
            int q = q0 + wr + i * 16 + orow + r;
            unsigned short* dst = mixBf + ((size_t)b * Q_N + q) * H_N + (h0 + wc + ocol);
#pragma unroll
            for (int j = 0; j < 4; j++) dst[j * 16] = f2bf(acc[i][j][r]);
        }
}

// ---------------- K4: out = tanh([mix | output] . W^T + b) ----------------
__global__ __launch_bounds__(256, 2)
void k_outlin(const unsigned short* __restrict__ mixBf, const unsigned short* __restrict__ outHi,
              const unsigned short* __restrict__ Whi, const float* __restrict__ bias,
              float* __restrict__ out) {
    __shared__ unsigned short At[128 * 32], Bt[128 * 32];
    const int r0 = blockIdx.y * 128;
    const int h0 = blockIdx.x * 128;
    const int lane = threadIdx.x & 63;
    const int w = threadIdx.x >> 6;
    const int wr = (w >> 1) * 64;
    const int wc = (w & 1) * 64;
    const int fm = lane & 15;
    const int fg = (lane >> 4) * 8;

    f32x4 acc[4][4];
#pragma unroll
    for (int i = 0; i < 4; i++)
#pragma unroll
        for (int j = 0; j < 4; j++) acc[i][j] = (f32x4){0.f, 0.f, 0.f, 0.f};

    for (int kc = 0; kc < C_N; kc += 32) {
        const unsigned short* Ag = (kc < H_N)
            ? mixBf + (size_t)r0 * H_N + kc
            : outHi + (size_t)r0 * H_N + (kc - H_N);
        stage_tile(Ag, H_N, At);
        stage_tile(Whi + (size_t)h0 * C_N + kc, C_N, Bt);
        __syncthreads();
        bf16x8 a[4], bb[4];
#pragma unroll
        for (int i = 0; i < 4; i++) {
            a[i] = *(const bf16x8*)&At[(wr + i * 16 + fm) * 32 + fg];
            bb[i] = *(const bf16x8*)&Bt[(wc + i * 16 + fm) * 32 + fg];
        }
#pragma unroll
        for (int i = 0; i < 4; i++)
#pragma unroll
            for (int j = 0; j < 4; j++) acc[i][j] = mfma16(a[i], bb[j], acc[i][j]);
        __syncthreads();
    }
    const int orow = (lane >> 4) * 4;
    const int ocol = lane & 15;
#pragma unroll
    for (int i = 0; i < 4; i++)
#pragma unroll
        for (int r = 0; r < 4; r++) {
            int rr = r0 + wr + i * 16 + orow + r;
#pragma unroll
            for (int j = 0; j < 4; j++) {
                int h = h0 + wc + j * 16 + ocol;
                float v = acc[i][j][r] + bias[h];
                out[(size_t)rr * H_N + h] = tanhf(v);
            }
        }
}

extern "C" void kernel_launch(void* const* d_in, const int* in_sizes, int n_in,
                              void* d_out, int out_size, void* d_ws, size_t ws_size,
                              hipStream_t stream) {
    const float* d_output  = (const float*)d_in[0]; // [8,1024,512]
    const float* d_context = (const float*)d_in[1]; // [8,4096,512]
    const int*   d_mask    = (const int*)d_in[2];   // [8,1024,4096]
    const float* d_W       = (const float*)d_in[3]; // [512,1024]
    const float* d_bias    = (const float*)d_in[4]; // [512]

    float* out_res = (float*)d_out;                          // [8,1024,512]
    float* attn    = out_res + (size_t)R_N * H_N;            // [8,1024,4096]

    char* ws = (char*)d_ws;
    unsigned short* ctxHi = (unsigned short*)ws; ws += (size_t)B_N * K_N * H_N * 2;
    unsigned short* ctxLo = (unsigned short*)ws; ws += (size_t)B_N * K_N * H_N * 2;
    unsigned short* ctxT  = (unsigned short*)ws; ws += (size_t)B_N * K_N * H_N * 2;
    unsigned short* outHi = (unsigned short*)ws; ws += (size_t)R_N * H_N * 2;
    unsigned short* outLo = (unsigned short*)ws; ws += (size_t)R_N * H_N * 2;
    unsigned short* Whi   = (unsigned short*)ws; ws += (size_t)H_N * C_N * 2;
    unsigned short* pBf   = (unsigned short*)ws; ws += (size_t)R_N * K_N * 2;
    unsigned short* mixBf = (unsigned short*)ws; ws += (size_t)R_N * H_N * 2;

    // K0: precision split / cvt / fused ctx split+transpose
    k_split<<<dim3((R_N * H_N / 4) / 256), 256, 0, stream>>>(d_output, outHi, outLo, R_N * H_N / 4);
    k_cvt<<<dim3((H_N * C_N / 4) / 256), 256, 0, stream>>>(d_W, Whi, H_N * C_N / 4);
    k_prep_ctx<<<dim3(K_N / 64, H_N / 64, B_N), 256, 0, stream>>>(d_context, ctxHi, ctxLo, ctxT);

    // K1: raw scores + mask into attn region
    k_scores<<<dim3(K_N / 128, Q_N / 128, B_N), 256, 0, stream>>>(outHi, outLo, ctxHi, ctxLo,
                                                                  d_mask, attn);

    // K2: softmax in place (mask already applied), bf16 copy of P
    k_softmax<<<dim3(R_N), 256, 0, stream>>>(attn, pBf);

    // K3: mix = P . context
    k_mix<<<dim3(H_N / 128, Q_N / 128, B_N), 256, 0, stream>>>(pBf, ctxT, mixBf);

    // K4: final linear + tanh
    k_outlin<<<dim3(H_N / 128, R_N / 128), 256, 0, stream>>>(mixBf, outHi, Whi, d_bias, out_res);
}

// Round 3
// 557.155 us; speedup vs baseline: 1.0581x; 1.0581x over previous
//
#include <hip/hip_runtime.h>
#include <cstdint>
#include <cstddef>

#define B_N 8
#define Q_N 1024
#define K_N 4096
#define H_N 512
#define C_N 1024
#define R_N (B_N * Q_N)

typedef short bf16x8 __attribute__((ext_vector_type(8)));
typedef float f32x4 __attribute__((ext_vector_type(4)));

typedef const void __attribute__((address_space(1))) gas_void;
typedef void __attribute__((address_space(3))) las_void;

__device__ __forceinline__ unsigned short f2bf(float f) {
    union { float f; unsigned u; } v; v.f = f;
    unsigned u = v.u;
    u += 0x7FFFu + ((u >> 16) & 1u);   // RNE
    return (unsigned short)(u >> 16);
}
__device__ __forceinline__ float bf2f(unsigned short h) {
    union { unsigned u; float f; } v; v.u = ((unsigned)h) << 16;
    return v.f;
}

__device__ __forceinline__ f32x4 mfma16(bf16x8 a, bf16x8 b, f32x4 c) {
    return __builtin_amdgcn_mfma_f32_16x16x32_bf16(a, b, c, 0, 0, 0);
}

// ---------------- K0a: fp32 -> bf16 hi/lo split ----------------
__global__ void k_split(const float* __restrict__ x, unsigned short* __restrict__ hi,
                        unsigned short* __restrict__ lo, int n4) {
    int i = blockIdx.x * 256 + threadIdx.x;
    if (i >= n4) return;
    float4 v = reinterpret_cast<const float4*>(x)[i];
    ushort4 h, l;
    h.x = f2bf(v.x); l.x = f2bf(v.x - bf2f(h.x));
    h.y = f2bf(v.y); l.y = f2bf(v.y - bf2f(h.y));
    h.z = f2bf(v.z); l.z = f2bf(v.z - bf2f(h.z));
    h.w = f2bf(v.w); l.w = f2bf(v.w - bf2f(h.w));
    reinterpret_cast<ushort4*>(hi)[i] = h;
    reinterpret_cast<ushort4*>(lo)[i] = l;
}

__global__ void k_cvt(const float* __restrict__ x, unsigned short* __restrict__ hi, int n4) {
    int i = blockIdx.x * 256 + threadIdx.x;
    if (i >= n4) return;
    float4 v = reinterpret_cast<const float4*>(x)[i];
    ushort4 h;
    h.x = f2bf(v.x); h.y = f2bf(v.y); h.z = f2bf(v.z); h.w = f2bf(v.w);
    reinterpret_cast<ushort4*>(hi)[i] = h;
}

// ---------------- K0b: fused context split + transpose (vectorized) ----------------
__global__ __launch_bounds__(256)
void k_prep_ctx(const float* __restrict__ ctx, unsigned short* __restrict__ ctxHi,
                unsigned short* __restrict__ ctxLo, unsigned short* __restrict__ ctxT) {
    __shared__ unsigned short tile[64][66];
    const int b = blockIdx.z;
    const int k0 = blockIdx.x * 64;
    const int h0 = blockIdx.y * 64;
    const int tx = threadIdx.x & 15;
    const int ty = threadIdx.x >> 4;
#pragma unroll
    for (int r = 0; r < 64; r += 16) {
        const int k = ty + r;
        const size_t go = ((size_t)b * K_N + k0 + k) * H_N + h0 + tx * 4;
        float4 v = *reinterpret_cast<const float4*>(ctx + go);
        ushort4 h, l;
        h.x = f2bf(v.x); l.x = f2bf(v.x - bf2f(h.x));
        h.y = f2bf(v.y); l.y = f2bf(v.y - bf2f(h.y));
        h.z = f2bf(v.z); l.z = f2bf(v.z - bf2f(h.z));
        h.w = f2bf(v.w); l.w = f2bf(v.w - bf2f(h.w));
        *reinterpret_cast<ushort4*>(ctxHi + go) = h;
        *reinterpret_cast<ushort4*>(ctxLo + go) = l;
        tile[tx * 4 + 0][k] = h.x;
        tile[tx * 4 + 1][k] = h.y;
        tile[tx * 4 + 2][k] = h.z;
        tile[tx * 4 + 3][k] = h.w;
    }
    __syncthreads();
#pragma unroll
    for (int r = 0; r < 64; r += 16) {
        const int h = ty + r;
        ushort4 t4 = *reinterpret_cast<const ushort4*>(&tile[h][tx * 4]);
        *reinterpret_cast<ushort4*>(ctxT + ((size_t)b * H_N + h0 + h) * K_N + k0 + tx * 4) = t4;
    }
}

// ---------------- async stage helpers (global -> LDS, 16B/lane, lane-order) ----------------
// 128 rows x 32 k (two passes of 256 lanes)
__device__ __forceinline__ void stage_tile(const unsigned short* __restrict__ g, int ld,
                                           unsigned short* __restrict__ lds) {
    const int t = threadIdx.x;
    const int wbase = t & ~63;
#pragma unroll
    for (int i = 0; i < 2; i++) {
        int idx = i * 256 + t;
        const unsigned short* ga = g + (size_t)(idx >> 2) * ld + (idx & 3) * 8;
        unsigned short* la = lds + (size_t)(i * 256 + wbase) * 8;
        __builtin_amdgcn_global_load_lds((gas_void*)ga, (las_void*)la, 16, 0, 0);
    }
}
// 64 rows x 32 k (single pass)
__device__ __forceinline__ void stage_tile64(const unsigned short* __restrict__ g, int ld,
                                             unsigned short* __restrict__ lds) {
    const int t = threadIdx.x;
    const unsigned short* ga = g + (size_t)(t >> 2) * ld + (t & 3) * 8;
    unsigned short* la = lds + (size_t)(t & ~63) * 8;
    __builtin_amdgcn_global_load_lds((gas_void*)ga, (las_void*)la, 16, 0, 0);
}

// ---------------- K1: S = output . context^T  (bf16x3 split), raw scores ----------------
__global__ __launch_bounds__(256, 2)
void k_scores(const unsigned short* __restrict__ outHi, const unsigned short* __restrict__ outLo,
              const unsigned short* __restrict__ ctxHi, const unsigned short* __restrict__ ctxLo,
              float* __restrict__ S) {
    __shared__ unsigned short Ah[128 * 32], Al[128 * 32], Bh[128 * 32], Bl[128 * 32];
    const int b = blockIdx.z;
    const int q0 = blockIdx.y * 128;
    const int k0 = blockIdx.x * 128;
    const unsigned short* Ahg = outHi + ((size_t)b * Q_N + q0) * H_N;
    const unsigned short* Alg = outLo + ((size_t)b * Q_N + q0) * H_N;
    const unsigned short* Bhg = ctxHi + ((size_t)b * K_N + k0) * H_N;
    const unsigned short* Blg = ctxLo + ((size_t)b * K_N + k0) * H_N;
    const int lane = threadIdx.x & 63;
    const int w = threadIdx.x >> 6;
    const int wr = (w >> 1) * 64;
    const int wc = (w & 1) * 64;
    const int fm = lane & 15;
    const int fg = (lane >> 4) * 8;

    f32x4 acc[4][4];
#pragma unroll
    for (int i = 0; i < 4; i++)
#pragma unroll
        for (int j = 0; j < 4; j++) acc[i][j] = (f32x4){0.f, 0.f, 0.f, 0.f};

    for (int kc = 0; kc < H_N; kc += 32) {
        stage_tile(Ahg + kc, H_N, Ah);
        stage_tile(Alg + kc, H_N, Al);
        stage_tile(Bhg + kc, H_N, Bh);
        stage_tile(Blg + kc, H_N, Bl);
        __syncthreads();
        bf16x8 ah[4], al[4], bh[4], bl[4];
#pragma unroll
        for (int i = 0; i < 4; i++) {
            ah[i] = *(const bf16x8*)&Ah[(wr + i * 16 + fm) * 32 + fg];
            al[i] = *(const bf16x8*)&Al[(wr + i * 16 + fm) * 32 + fg];
            bh[i] = *(const bf16x8*)&Bh[(wc + i * 16 + fm) * 32 + fg];
            bl[i] = *(const bf16x8*)&Bl[(wc + i * 16 + fm) * 32 + fg];
        }
#pragma unroll
        for (int i = 0; i < 4; i++)
#pragma unroll
            for (int j = 0; j < 4; j++) {
                acc[i][j] = mfma16(ah[i], bh[j], acc[i][j]);
                acc[i][j] = mfma16(ah[i], bl[j], acc[i][j]);
                acc[i][j] = mfma16(al[i], bh[j], acc[i][j]);
            }
        __syncthreads();
    }
    float* Sb = S + (size_t)b * Q_N * K_N;
    const int orow = (lane >> 4) * 4;
    const int ocol = lane & 15;
#pragma unroll
    for (int i = 0; i < 4; i++)
#pragma unroll
        for (int r = 0; r < 4; r++) {
            int q = q0 + wr + i * 16 + orow + r;
            float* dst = Sb + (size_t)q * K_N + (k0 + wc + ocol);
#pragma unroll
            for (int j = 0; j < 4; j++) dst[j * 16] = acc[i][j][r];
        }
}

// ---------------- K2: masked row softmax (coalesced int4 mask), in-place + bf16 P ----------------
__global__ __launch_bounds__(256)
void k_softmax(float* __restrict__ S, const int* __restrict__ mask, unsigned short* __restrict__ pbf) {
    const size_t r = blockIdx.x;
    float* row = S + r * K_N;
    const int* mrow = mask + r * K_N;
    unsigned short* prow = pbf + r * K_N;
    const int t = threadIdx.x;

    float4 v[4];
    float lmax = -1e30f;
#pragma unroll
    for (int i = 0; i < 4; i++) {
        int idx = i * 256 + t;
        float4 s = reinterpret_cast<const float4*>(row)[idx];
        int4 mk = reinterpret_cast<const int4*>(mrow)[idx];
        s.x = mk.x ? -1e30f : s.x;
        s.y = mk.y ? -1e30f : s.y;
        s.z = mk.z ? -1e30f : s.z;
        s.w = mk.w ? -1e30f : s.w;
        v[i] = s;
        lmax = fmaxf(fmaxf(fmaxf(lmax, s.x), fmaxf(s.y, s.z)), s.w);
    }
#pragma unroll
    for (int off = 32; off >= 1; off >>= 1)
        lmax = fmaxf(lmax, __shfl_xor(lmax, off, 64));
    __shared__ float redm[4];
    __shared__ float reds[4];
    const int wv = t >> 6;
    if ((t & 63) == 0) redm[wv] = lmax;
    __syncthreads();
    const float m = fmaxf(fmaxf(redm[0], redm[1]), fmaxf(redm[2], redm[3]));

    float4 e[4];
    float lsum = 0.f;
#pragma unroll
    for (int i = 0; i < 4; i++) {
        e[i].x = __expf(v[i].x - m);
        e[i].y = __expf(v[i].y - m);
        e[i].z = __expf(v[i].z - m);
        e[i].w = __expf(v[i].w - m);
        lsum += (e[i].x + e[i].y) + (e[i].z + e[i].w);
    }
#pragma unroll
    for (int off = 32; off >= 1; off >>= 1)
        lsum += __shfl_xor(lsum, off, 64);
    if ((t & 63) == 0) reds[wv] = lsum;
    __syncthreads();
    const float inv = 1.0f / (reds[0] + reds[1] + reds[2] + reds[3]);

#pragma unroll
    for (int i = 0; i < 4; i++) {
        int idx = i * 256 + t;
        float4 p;
        p.x = e[i].x * inv; p.y = e[i].y * inv; p.z = e[i].z * inv; p.w = e[i].w * inv;
        reinterpret_cast<float4*>(row)[idx] = p;
        ushort4 pb;
        pb.x = f2bf(p.x); pb.y = f2bf(p.y); pb.z = f2bf(p.z); pb.w = f2bf(p.w);
        reinterpret_cast<ushort4*>(prow)[idx] = pb;
    }
}

// ---------------- K3: mix = P . ctxT^T, 128x64 tile (2 blocks/CU), BK=64 ----------------
__global__ __launch_bounds__(256, 2)
void k_mix(const unsigned short* __restrict__ P, const unsigned short* __restrict__ ctxT,
           unsigned short* __restrict__ mixBf) {
    __shared__ unsigned short A0[128 * 32], A1[128 * 32], B0[64 * 32], B1[64 * 32];
    const int b = blockIdx.z;
    const int q0 = blockIdx.y * 128;
    const int h0 = blockIdx.x * 64;
    const unsigned short* Ag = P + ((size_t)b * Q_N + q0) * K_N;
    const unsigned short* Bg = ctxT + ((size_t)b * H_N + h0) * K_N;
    const int lane = threadIdx.x & 63;
    const int w = threadIdx.x >> 6;
    const int wr = w * 32;              // each wave: 32 rows x 64 cols
    const int fm = lane & 15;
    const int fg = (lane >> 4) * 8;

    f32x4 acc[2][4];
#pragma unroll
    for (int i = 0; i < 2; i++)
#pragma unroll
        for (int j = 0; j < 4; j++) acc[i][j] = (f32x4){0.f, 0.f, 0.f, 0.f};

    for (int kc = 0; kc < K_N; kc += 64) {
        stage_tile(Ag + kc, K_N, A0);
        stage_tile(Ag + kc + 32, K_N, A1);
        stage_tile64(Bg + kc, K_N, B0);
        stage_tile64(Bg + kc + 32, K_N, B1);
        __syncthreads();
        bf16x8 a[2], bb[4];
#pragma unroll
        for (int i = 0; i < 2; i++) a[i] = *(const bf16x8*)&A0[(wr + i * 16 + fm) * 32 + fg];
#pragma unroll
        for (int j = 0; j < 4; j++) bb[j] = *(const bf16x8*)&B0[(j * 16 + fm) * 32 + fg];
#pragma unroll
        for (int i = 0; i < 2; i++)
#pragma unroll
            for (int j = 0; j < 4; j++) acc[i][j] = mfma16(a[i], bb[j], acc[i][j]);
#pragma unroll
        for (int i = 0; i < 2; i++) a[i] = *(const bf16x8*)&A1[(wr + i * 16 + fm) * 32 + fg];
#pragma unroll
        for (int j = 0; j < 4; j++) bb[j] = *(const bf16x8*)&B1[(j * 16 + fm) * 32 + fg];
#pragma unroll
        for (int i = 0; i < 2; i++)
#pragma unroll
            for (int j = 0; j < 4; j++) acc[i][j] = mfma16(a[i], bb[j], acc[i][j]);
        __syncthreads();
    }
    const int orow = (lane >> 4) * 4;
    const int ocol = lane & 15;
#pragma unroll
    for (int i = 0; i < 2; i++)
#pragma unroll
        for (int r = 0; r < 4; r++) {
            int q = q0 + wr + i * 16 + orow + r;
            unsigned short* dst = mixBf + ((size_t)b * Q_N + q) * H_N + (h0 + ocol);
#pragma unroll
            for (int j = 0; j < 4; j++) dst[j * 16] = f2bf(acc[i][j][r]);
        }
}

// ---------------- K4: out = tanh([mix | output] . W^T + b), 128x64 tile ----------------
__global__ __launch_bounds__(256, 2)
void k_outlin(const unsigned short* __restrict__ mixBf, const unsigned short* __restrict__ outHi,
              const unsigned short* __restrict__ Whi, const float* __restrict__ bias,
              float* __restrict__ out) {
    __shared__ unsigned short At[128 * 32], Bt[64 * 32];
    const int r0 = blockIdx.y * 128;
    const int h0 = blockIdx.x * 64;
    const int lane = threadIdx.x & 63;
    const int w = threadIdx.x >> 6;
    const int wr = w * 32;
    const int fm = lane & 15;
    const int fg = (lane >> 4) * 8;

    f32x4 acc[2][4];
#pragma unroll
    for (int i = 0; i < 2; i++)
#pragma unroll
        for (int j = 0; j < 4; j++) acc[i][j] = (f32x4){0.f, 0.f, 0.f, 0.f};

    for (int kc = 0; kc < C_N; kc += 32) {
        const unsigned short* Ag = (kc < H_N)
            ? mixBf + (size_t)r0 * H_N + kc
            : outHi + (size_t)r0 * H_N + (kc - H_N);
        stage_tile(Ag, H_N, At);
        stage_tile64(Whi + (size_t)h0 * C_N + kc, C_N, Bt);
        __syncthreads();
        bf16x8 a[2], bb[4];
#pragma unroll
        for (int i = 0; i < 2; i++) a[i] = *(const bf16x8*)&At[(wr + i * 16 + fm) * 32 + fg];
#pragma unroll
        for (int j = 0; j < 4; j++) bb[j] = *(const bf16x8*)&Bt[(j * 16 + fm) * 32 + fg];
#pragma unroll
        for (int i = 0; i < 2; i++)
#pragma unroll
            for (int j = 0; j < 4; j++) acc[i][j] = mfma16(a[i], bb[j], acc[i][j]);
        __syncthreads();
    }
    const int orow = (lane >> 4) * 4;
    const int ocol = lane & 15;
#pragma unroll
    for (int i = 0; i < 2; i++)
#pragma unroll
        for (int r = 0; r < 4; r++) {
            int rr = r0 + wr + i * 16 + orow + r;
#pragma unroll
            for (int j = 0; j < 4; j++) {
                int h = h0 + j * 16 + ocol;
                float v = acc[i][j][r] + bias[h];
                out[(size_t)rr * H_N + h] = tanhf(v);
            }
        }
}

extern "C" void kernel_launch(void* const* d_in, const int* in_sizes, int n_in,
                              void* d_out, int out_size, void* d_ws, size_t ws_size,
                              hipStream_t stream) {
    const float* d_output  = (const float*)d_in[0];
    const float* d_context = (const float*)d_in[1];
    const int*   d_mask    = (const int*)d_in[2];
    const float* d_W       = (const float*)d_in[3];
    const float* d_bias    = (const float*)d_in[4];

    float* out_res = (float*)d_out;
    float* attn    = out_res + (size_t)R_N * H_N;

    char* ws = (char*)d_ws;
    unsigned short* ctxHi = (unsigned short*)ws; ws += (size_t)B_N * K_N * H_N * 2;
    unsigned short* ctxLo = (unsigned short*)ws; ws += (size_t)B_N * K_N * H_N * 2;
    unsigned short* ctxT  = (unsigned short*)ws; ws += (size_t)B_N * K_N * H_N * 2;
    unsigned short* outHi = (unsigned short*)ws; ws += (size_t)R_N * H_N * 2;
    unsigned short* outLo = (unsigned short*)ws; ws += (size_t)R_N * H_N * 2;
    unsigned short* Whi   = (unsigned short*)ws; ws += (size_t)H_N * C_N * 2;
    unsigned short* pBf   = (unsigned short*)ws; ws += (size_t)R_N * K_N * 2;
    unsigned short* mixBf = (unsigned short*)ws; ws += (size_t)R_N * H_N * 2;

    k_split<<<dim3((R_N * H_N / 4) / 256), 256, 0, stream>>>(d_output, outHi, outLo, R_N * H_N / 4);
    k_cvt<<<dim3((H_N * C_N / 4) / 256), 256, 0, stream>>>(d_W, Whi, H_N * C_N / 4);
    k_prep_ctx<<<dim3(K_N / 64, H_N / 64, B_N), 256, 0, stream>>>(d_context, ctxHi, ctxLo, ctxT);

    k_scores<<<dim3(K_N / 128, Q_N / 128, B_N), 256, 0, stream>>>(outHi, outLo, ctxHi, ctxLo, attn);

    k_softmax<<<dim3(R_N), 256, 0, stream>>>(attn, d_mask, pBf);

    k_mix<<<dim3(H_N / 64, Q_N / 128, B_N), 256, 0, stream>>>(pBf, ctxT, mixBf);

    k_outlin<<<dim3(H_N / 64, R_N / 128), 256, 0, stream>>>(mixBf, outHi, Whi, d_bias, out_res);
}

// Round 4
// 539.447 us; speedup vs baseline: 1.0928x; 1.0328x over previous
//
#include <hip/hip_runtime.h>
#include <cstdint>
#include <cstddef>

#define B_N 8
#define Q_N 1024
#define K_N 4096
#define H_N 512
#define C_N 1024
#define R_N (B_N * Q_N)

typedef short bf16x8 __attribute__((ext_vector_type(8)));
typedef float f32x4 __attribute__((ext_vector_type(4)));

typedef const void __attribute__((address_space(1))) gas_void;
typedef void __attribute__((address_space(3))) las_void;

__device__ __forceinline__ unsigned short f2bf(float f) {
    union { float f; unsigned u; } v; v.f = f;
    unsigned u = v.u;
    u += 0x7FFFu + ((u >> 16) & 1u);   // RNE
    return (unsigned short)(u >> 16);
}
__device__ __forceinline__ float bf2f(unsigned short h) {
    union { unsigned u; float f; } v; v.u = ((unsigned)h) << 16;
    return v.f;
}

__device__ __forceinline__ f32x4 mfma16(bf16x8 a, bf16x8 b, f32x4 c) {
    return __builtin_amdgcn_mfma_f32_16x16x32_bf16(a, b, c, 0, 0, 0);
}

// ---------------- K0a: merged output hi/lo split + W cvt (one launch) ----------------
__global__ void k_split_cvt(const float* __restrict__ outp, unsigned short* __restrict__ outHi,
                            unsigned short* __restrict__ outLo, const float* __restrict__ W,
                            unsigned short* __restrict__ Whi) {
    const int n4a = R_N * H_N / 4;
    const int n4b = H_N * C_N / 4;
    int i = blockIdx.x * 256 + threadIdx.x;
    if (i < n4a) {
        float4 v = reinterpret_cast<const float4*>(outp)[i];
        ushort4 h, l;
        h.x = f2bf(v.x); l.x = f2bf(v.x - bf2f(h.x));
        h.y = f2bf(v.y); l.y = f2bf(v.y - bf2f(h.y));
        h.z = f2bf(v.z); l.z = f2bf(v.z - bf2f(h.z));
        h.w = f2bf(v.w); l.w = f2bf(v.w - bf2f(h.w));
        reinterpret_cast<ushort4*>(outHi)[i] = h;
        reinterpret_cast<ushort4*>(outLo)[i] = l;
    } else {
        int j = i - n4a;
        if (j < n4b) {
            float4 v = reinterpret_cast<const float4*>(W)[j];
            ushort4 h;
            h.x = f2bf(v.x); h.y = f2bf(v.y); h.z = f2bf(v.z); h.w = f2bf(v.w);
            reinterpret_cast<ushort4*>(Whi)[j] = h;
        }
    }
}

// ---------------- K0b: fused context split + transpose (vectorized) ----------------
__global__ __launch_bounds__(256)
void k_prep_ctx(const float* __restrict__ ctx, unsigned short* __restrict__ ctxHi,
                unsigned short* __restrict__ ctxLo, unsigned short* __restrict__ ctxT) {
    __shared__ unsigned short tile[64][66];
    const int b = blockIdx.z;
    const int k0 = blockIdx.x * 64;
    const int h0 = blockIdx.y * 64;
    const int tx = threadIdx.x & 15;
    const int ty = threadIdx.x >> 4;
#pragma unroll
    for (int r = 0; r < 64; r += 16) {
        const int k = ty + r;
        const size_t go = ((size_t)b * K_N + k0 + k) * H_N + h0 + tx * 4;
        float4 v = *reinterpret_cast<const float4*>(ctx + go);
        ushort4 h, l;
        h.x = f2bf(v.x); l.x = f2bf(v.x - bf2f(h.x));
        h.y = f2bf(v.y); l.y = f2bf(v.y - bf2f(h.y));
        h.z = f2bf(v.z); l.z = f2bf(v.z - bf2f(h.z));
        h.w = f2bf(v.w); l.w = f2bf(v.w - bf2f(h.w));
        *reinterpret_cast<ushort4*>(ctxHi + go) = h;
        *reinterpret_cast<ushort4*>(ctxLo + go) = l;
        tile[tx * 4 + 0][k] = h.x;
        tile[tx * 4 + 1][k] = h.y;
        tile[tx * 4 + 2][k] = h.z;
        tile[tx * 4 + 3][k] = h.w;
    }
    __syncthreads();
#pragma unroll
    for (int r = 0; r < 64; r += 16) {
        const int h = ty + r;
        ushort4 t4 = *reinterpret_cast<const ushort4*>(&tile[h][tx * 4]);
        *reinterpret_cast<ushort4*>(ctxT + ((size_t)b * H_N + h0 + h) * K_N + k0 + tx * 4) = t4;
    }
}

// ---------------- async stage helpers (global -> LDS, 16B/lane, lane-order) ----------------
__device__ __forceinline__ void stage_tile(const unsigned short* __restrict__ g, int ld,
                                           unsigned short* __restrict__ lds) {
    const int t = threadIdx.x;
    const int wbase = t & ~63;
#pragma unroll
    for (int i = 0; i < 2; i++) {
        int idx = i * 256 + t;
        const unsigned short* ga = g + (size_t)(idx >> 2) * ld + (idx & 3) * 8;
        unsigned short* la = lds + (size_t)(i * 256 + wbase) * 8;
        __builtin_amdgcn_global_load_lds((gas_void*)ga, (las_void*)la, 16, 0, 0);
    }
}
__device__ __forceinline__ void stage_tile64(const unsigned short* __restrict__ g, int ld,
                                             unsigned short* __restrict__ lds) {
    const int t = threadIdx.x;
    const unsigned short* ga = g + (size_t)(t >> 2) * ld + (t & 3) * 8;
    unsigned short* la = lds + (size_t)(t & ~63) * 8;
    __builtin_amdgcn_global_load_lds((gas_void*)ga, (las_void*)la, 16, 0, 0);
}

// ---------------- K1: S = output . context^T  (bf16x3 split), raw scores ----------------
__global__ __launch_bounds__(256, 2)
void k_scores(const unsigned short* __restrict__ outHi, const unsigned short* __restrict__ outLo,
              const unsigned short* __restrict__ ctxHi, const unsigned short* __restrict__ ctxLo,
              float* __restrict__ S) {
    __shared__ unsigned short Ah[128 * 32], Al[128 * 32], Bh[128 * 32], Bl[128 * 32];
    const int b = blockIdx.z;
    const int q0 = blockIdx.y * 128;
    const int k0 = blockIdx.x * 128;
    const unsigned short* Ahg = outHi + ((size_t)b * Q_N + q0) * H_N;
    const unsigned short* Alg = outLo + ((size_t)b * Q_N + q0) * H_N;
    const unsigned short* Bhg = ctxHi + ((size_t)b * K_N + k0) * H_N;
    const unsigned short* Blg = ctxLo + ((size_t)b * K_N + k0) * H_N;
    const int lane = threadIdx.x & 63;
    const int w = threadIdx.x >> 6;
    const int wr = (w >> 1) * 64;
    const int wc = (w & 1) * 64;
    const int fm = lane & 15;
    const int fg = (lane >> 4) * 8;

    f32x4 acc[4][4];
#pragma unroll
    for (int i = 0; i < 4; i++)
#pragma unroll
        for (int j = 0; j < 4; j++) acc[i][j] = (f32x4){0.f, 0.f, 0.f, 0.f};

    for (int kc = 0; kc < H_N; kc += 32) {
        stage_tile(Ahg + kc, H_N, Ah);
        stage_tile(Alg + kc, H_N, Al);
        stage_tile(Bhg + kc, H_N, Bh);
        stage_tile(Blg + kc, H_N, Bl);
        __syncthreads();
        bf16x8 ah[4], al[4], bh[4], bl[4];
#pragma unroll
        for (int i = 0; i < 4; i++) {
            ah[i] = *(const bf16x8*)&Ah[(wr + i * 16 + fm) * 32 + fg];
            al[i] = *(const bf16x8*)&Al[(wr + i * 16 + fm) * 32 + fg];
            bh[i] = *(const bf16x8*)&Bh[(wc + i * 16 + fm) * 32 + fg];
            bl[i] = *(const bf16x8*)&Bl[(wc + i * 16 + fm) * 32 + fg];
        }
#pragma unroll
        for (int i = 0; i < 4; i++)
#pragma unroll
            for (int j = 0; j < 4; j++) {
                acc[i][j] = mfma16(ah[i], bh[j], acc[i][j]);
                acc[i][j] = mfma16(ah[i], bl[j], acc[i][j]);
                acc[i][j] = mfma16(al[i], bh[j], acc[i][j]);
            }
        __syncthreads();
    }
    float* Sb = S + (size_t)b * Q_N * K_N;
    const int orow = (lane >> 4) * 4;
    const int ocol = lane & 15;
#pragma unroll
    for (int i = 0; i < 4; i++)
#pragma unroll
        for (int r = 0; r < 4; r++) {
            int q = q0 + wr + i * 16 + orow + r;
            float* dst = Sb + (size_t)q * K_N + (k0 + wc + ocol);
#pragma unroll
            for (int j = 0; j < 4; j++) dst[j * 16] = acc[i][j][r];
        }
}

// ---------------- K2: masked row softmax, in-place + bf16 P ----------------
__global__ __launch_bounds__(256)
void k_softmax(float* __restrict__ S, const int* __restrict__ mask, unsigned short* __restrict__ pbf) {
    const size_t r = blockIdx.x;
    float* row = S + r * K_N;
    const int* mrow = mask + r * K_N;
    unsigned short* prow = pbf + r * K_N;
    const int t = threadIdx.x;

    float4 v[4];
    float lmax = -1e30f;
#pragma unroll
    for (int i = 0; i < 4; i++) {
        int idx = i * 256 + t;
        float4 s = reinterpret_cast<const float4*>(row)[idx];
        int4 mk = reinterpret_cast<const int4*>(mrow)[idx];
        s.x = mk.x ? -1e30f : s.x;
        s.y = mk.y ? -1e30f : s.y;
        s.z = mk.z ? -1e30f : s.z;
        s.w = mk.w ? -1e30f : s.w;
        v[i] = s;
        lmax = fmaxf(fmaxf(fmaxf(lmax, s.x), fmaxf(s.y, s.z)), s.w);
    }
#pragma unroll
    for (int off = 32; off >= 1; off >>= 1)
        lmax = fmaxf(lmax, __shfl_xor(lmax, off, 64));
    __shared__ float redm[4];
    __shared__ float reds[4];
    const int wv = t >> 6;
    if ((t & 63) == 0) redm[wv] = lmax;
    __syncthreads();
    const float m = fmaxf(fmaxf(redm[0], redm[1]), fmaxf(redm[2], redm[3]));

    float4 e[4];
    float lsum = 0.f;
#pragma unroll
    for (int i = 0; i < 4; i++) {
        e[i].x = __expf(v[i].x - m);
        e[i].y = __expf(v[i].y - m);
        e[i].z = __expf(v[i].z - m);
        e[i].w = __expf(v[i].w - m);
        lsum += (e[i].x + e[i].y) + (e[i].z + e[i].w);
    }
#pragma unroll
    for (int off = 32; off >= 1; off >>= 1)
        lsum += __shfl_xor(lsum, off, 64);
    if ((t & 63) == 0) reds[wv] = lsum;
    __syncthreads();
    const float inv = 1.0f / (reds[0] + reds[1] + reds[2] + reds[3]);

#pragma unroll
    for (int i = 0; i < 4; i++) {
        int idx = i * 256 + t;
        float4 p;
        p.x = e[i].x * inv; p.y = e[i].y * inv; p.z = e[i].z * inv; p.w = e[i].w * inv;
        reinterpret_cast<float4*>(row)[idx] = p;
        ushort4 pb;
        pb.x = f2bf(p.x); pb.y = f2bf(p.y); pb.z = f2bf(p.z); pb.w = f2bf(p.w);
        reinterpret_cast<ushort4*>(prow)[idx] = pb;
    }
}

// ---------------- K3: mix partials = P . ctxT^T, 128x128 tile, K-split=2 ----------------
// grid (H/128=4, Q/128=8, B*2=16): one launch, 512 co-resident blocks (2/CU).
// Each block reduces K/2=2048 into fp32 partials (part + split*R_N*H_N).
__global__ __launch_bounds__(256, 2)
void k_mix(const unsigned short* __restrict__ P, const unsigned short* __restrict__ ctxT,
           float* __restrict__ part) {
    __shared__ unsigned short A0[128 * 32], A1[128 * 32], B0[128 * 32], B1[128 * 32];
    const int b = blockIdx.z >> 1;
    const int s = blockIdx.z & 1;
    const int kBase = s * (K_N / 2);
    const int q0 = blockIdx.y * 128;
    const int h0 = blockIdx.x * 128;
    const unsigned short* Ag = P + ((size_t)b * Q_N + q0) * K_N;
    const unsigned short* Bg = ctxT + ((size_t)b * H_N + h0) * K_N;
    const int lane = threadIdx.x & 63;
    const int w = threadIdx.x >> 6;
    const int wr = (w >> 1) * 64;
    const int wc = (w & 1) * 64;
    const int fm = lane & 15;
    const int fg = (lane >> 4) * 8;

    f32x4 acc[4][4];
#pragma unroll
    for (int i = 0; i < 4; i++)
#pragma unroll
        for (int j = 0; j < 4; j++) acc[i][j] = (f32x4){0.f, 0.f, 0.f, 0.f};

    for (int kc = kBase; kc < kBase + K_N / 2; kc += 64) {
        stage_tile(Ag + kc, K_N, A0);
        stage_tile(Ag + kc + 32, K_N, A1);
        stage_tile(Bg + kc, K_N, B0);
        stage_tile(Bg + kc + 32, K_N, B1);
        __syncthreads();
        bf16x8 a[4], bb[4];
#pragma unroll
        for (int i = 0; i < 4; i++) {
            a[i] = *(const bf16x8*)&A0[(wr + i * 16 + fm) * 32 + fg];
            bb[i] = *(const bf16x8*)&B0[(wc + i * 16 + fm) * 32 + fg];
        }
#pragma unroll
        for (int i = 0; i < 4; i++)
#pragma unroll
            for (int j = 0; j < 4; j++) acc[i][j] = mfma16(a[i], bb[j], acc[i][j]);
#pragma unroll
        for (int i = 0; i < 4; i++) {
            a[i] = *(const bf16x8*)&A1[(wr + i * 16 + fm) * 32 + fg];
            bb[i] = *(const bf16x8*)&B1[(wc + i * 16 + fm) * 32 + fg];
        }
#pragma unroll
        for (int i = 0; i < 4; i++)
#pragma unroll
            for (int j = 0; j < 4; j++) acc[i][j] = mfma16(a[i], bb[j], acc[i][j]);
        __syncthreads();
    }
    float* dst0 = part + (size_t)s * R_N * H_N;
    const int orow = (lane >> 4) * 4;
    const int ocol = lane & 15;
#pragma unroll
    for (int i = 0; i < 4; i++)
#pragma unroll
        for (int r = 0; r < 4; r++) {
            int q = q0 + wr + i * 16 + orow + r;
            float* dst = dst0 + ((size_t)b * Q_N + q) * H_N + (h0 + wc + ocol);
#pragma unroll
            for (int j = 0; j < 4; j++) dst[j * 16] = acc[i][j][r];
        }
}

// ---------------- K3b: reduce partials -> bf16 mixBf ----------------
__global__ void k_reduce(const float* __restrict__ part, unsigned short* __restrict__ mixBf) {
    int i = blockIdx.x * 256 + threadIdx.x;         // i indexes float4 groups
    const float4 a = reinterpret_cast<const float4*>(part)[i];
    const float4 b = reinterpret_cast<const float4*>(part + (size_t)R_N * H_N)[i];
    ushort4 h;
    h.x = f2bf(a.x + b.x);
    h.y = f2bf(a.y + b.y);
    h.z = f2bf(a.z + b.z);
    h.w = f2bf(a.w + b.w);
    reinterpret_cast<ushort4*>(mixBf)[i] = h;
}

// ---------------- K4: out = tanh([mix | output] . W^T + b), 128x64 tile ----------------
__global__ __launch_bounds__(256, 2)
void k_outlin(const unsigned short* __restrict__ mixBf, const unsigned short* __restrict__ outHi,
              const unsigned short* __restrict__ Whi, const float* __restrict__ bias,
              float* __restrict__ out) {
    __shared__ unsigned short At[128 * 32], Bt[64 * 32];
    const int r0 = blockIdx.y * 128;
    const int h0 = blockIdx.x * 64;
    const int lane = threadIdx.x & 63;
    const int w = threadIdx.x >> 6;
    const int wr = w * 32;
    const int fm = lane & 15;
    const int fg = (lane >> 4) * 8;

    f32x4 acc[2][4];
#pragma unroll
    for (int i = 0; i < 2; i++)
#pragma unroll
        for (int j = 0; j < 4; j++) acc[i][j] = (f32x4){0.f, 0.f, 0.f, 0.f};

    for (int kc = 0; kc < C_N; kc += 32) {
        const unsigned short* Ag = (kc < H_N)
            ? mixBf + (size_t)r0 * H_N + kc
            : outHi + (size_t)r0 * H_N + (kc - H_N);
        stage_tile(Ag, H_N, At);
        stage_tile64(Whi + (size_t)h0 * C_N + kc, C_N, Bt);
        __syncthreads();
        bf16x8 a[2], bb[4];
#pragma unroll
        for (int i = 0; i < 2; i++) a[i] = *(const bf16x8*)&At[(wr + i * 16 + fm) * 32 + fg];
#pragma unroll
        for (int j = 0; j < 4; j++) bb[j] = *(const bf16x8*)&Bt[(j * 16 + fm) * 32 + fg];
#pragma unroll
        for (int i = 0; i < 2; i++)
#pragma unroll
            for (int j = 0; j < 4; j++) acc[i][j] = mfma16(a[i], bb[j], acc[i][j]);
        __syncthreads();
    }
    const int orow = (lane >> 4) * 4;
    const int ocol = lane & 15;
#pragma unroll
    for (int i = 0; i < 2; i++)
#pragma unroll
        for (int r = 0; r < 4; r++) {
            int rr = r0 + wr + i * 16 + orow + r;
#pragma unroll
            for (int j = 0; j < 4; j++) {
                int h = h0 + j * 16 + ocol;
                float v = acc[i][j][r] + bias[h];
                out[(size_t)rr * H_N + h] = tanhf(v);
            }
        }
}

extern "C" void kernel_launch(void* const* d_in, const int* in_sizes, int n_in,
                              void* d_out, int out_size, void* d_ws, size_t ws_size,
                              hipStream_t stream) {
    const float* d_output  = (const float*)d_in[0];
    const float* d_context = (const float*)d_in[1];
    const int*   d_mask    = (const int*)d_in[2];
    const float* d_W       = (const float*)d_in[3];
    const float* d_bias    = (const float*)d_in[4];

    float* out_res = (float*)d_out;
    float* attn    = out_res + (size_t)R_N * H_N;

    char* ws = (char*)d_ws;
    unsigned short* ctxHi = (unsigned short*)ws; ws += (size_t)B_N * K_N * H_N * 2;  // 32 MB
    unsigned short* ctxLo = (unsigned short*)ws; ws += (size_t)B_N * K_N * H_N * 2;  // 32 MB
    unsigned short* ctxT  = (unsigned short*)ws; ws += (size_t)B_N * K_N * H_N * 2;  // 32 MB
    unsigned short* outHi = (unsigned short*)ws; ws += (size_t)R_N * H_N * 2;
    unsigned short* outLo = (unsigned short*)ws; ws += (size_t)R_N * H_N * 2;
    unsigned short* Whi   = (unsigned short*)ws; ws += (size_t)H_N * C_N * 2;
    unsigned short* pBf   = (unsigned short*)ws; ws += (size_t)R_N * K_N * 2;        // 64 MB
    unsigned short* mixBf = (unsigned short*)ws; ws += (size_t)R_N * H_N * 2;

    // fp32 mix partials (2 x 16.8 MB) alias ctxHi (33.6 MB) — k_scores is done by then.
    float* part = (float*)ctxHi;

    const int n4_sc = R_N * H_N / 4 + H_N * C_N / 4;
    k_split_cvt<<<dim3((n4_sc + 255) / 256), 256, 0, stream>>>(d_output, outHi, outLo, d_W, Whi);
    k_prep_ctx<<<dim3(K_N / 64, H_N / 64, B_N), 256, 0, stream>>>(d_context, ctxHi, ctxLo, ctxT);

    k_scores<<<dim3(K_N / 128, Q_N / 128, B_N), 256, 0, stream>>>(outHi, outLo, ctxHi, ctxLo, attn);

    k_softmax<<<dim3(R_N), 256, 0, stream>>>(attn, d_mask, pBf);

    k_mix<<<dim3(H_N / 128, Q_N / 128, B_N * 2), 256, 0, stream>>>(pBf, ctxT, part);
    k_reduce<<<dim3((R_N * H_N / 4) / 256), 256, 0, stream>>>(part, mixBf);

    k_outlin<<<dim3(H_N / 64, R_N / 128), 256, 0, stream>>>(mixBf, outHi, Whi, d_bias, out_res);
}